// Round 10
// baseline (106.286 us; speedup 1.0000x reference)
//
#include <hip/hip_runtime.h>
#include <cstddef>

#define RR 80
#define NVIEW 4
#define CH 32
#define IH 64
#define IW 64
#define NPIX (IH*IW)
#define NVOX (RR*RR*RR)   // 512000

// G (f16) layout: [v][grp(4 x 8ch)][y][x][8 f16 = 16B]
#define PLANE_H (NPIX*8)
#define VIEW_H  (4*PLANE_H)

typedef _Float16 half2_t  __attribute__((ext_vector_type(2)));
typedef _Float16 half4_t  __attribute__((ext_vector_type(4)));
typedef _Float16 half8_t  __attribute__((ext_vector_type(8)));
typedef float    float4_t __attribute__((ext_vector_type(4)));

// ---------------------------------------------------------------------------
// G[v][g][y][x][e] = sum_ic feats[v][ic][y][x] * W1[ic][8*g+e]  (f16 output)
// ---------------------------------------------------------------------------
__global__ __launch_bounds__(256) void g_precompute(
    const float* __restrict__ feats, const float* __restrict__ W1,
    _Float16* __restrict__ G)
{
    int g = blockIdx.x >> 6;                        // 0..3 (8-ch group)
    int p = (blockIdx.x & 63)*256 + threadIdx.x;    // pixel 0..16383
    __shared__ float sW1[CH*8];
    if (threadIdx.x < CH*8) {
        int ic = threadIdx.x >> 3, e = threadIdx.x & 7;
        sW1[threadIdx.x] = W1[ic*CH + 8*g + e];
    }
    __syncthreads();
    int v  = p >> 12;
    int yx = p & 4095;
    const float* fb = feats + ((size_t)v*CH)*NPIX + yx;
    float acc[8];
    #pragma unroll
    for (int e=0;e<8;++e) acc[e] = 0.f;
    #pragma unroll
    for (int ic=0; ic<CH; ++ic) {
        float fv = fb[(size_t)ic*NPIX];
        #pragma unroll
        for (int e=0;e<8;++e) acc[e] = fmaf(fv, sW1[ic*8+e], acc[e]);
    }
    half8_t h;
    #pragma unroll
    for (int e=0;e<8;++e) h[e] = (_Float16)acc[e];
    *(half8_t*)(G + (size_t)v*VIEW_H + (size_t)g*PLANE_H + (size_t)yx*8) = h;
}

// ---------------------------------------------------------------------------
// Main: zero-LDS transposed MFMA MLP.  Projection is computed ONCE per
// (lane's own voxel, view) and shared to the 4 quads via ds_bpermute
// (3 dwords: 2 packed f16 weight pairs + offset|mk packet).
// ---------------------------------------------------------------------------
__global__ __launch_bounds__(256) void dgfv_main(
    const _Float16* __restrict__ G,   // [NVIEW][4][IH][IW][8]
    const float* __restrict__ poses,
    const float* __restrict__ b1,
    const float* __restrict__ W2, const float* __restrict__ b2,
    const float* __restrict__ W3, const float* __restrict__ b3,
    float* __restrict__ out)
{
    const int wid  = threadIdx.x >> 6;
    const int lane = threadIdx.x & 63;
    const int lq   = lane >> 4;
    const int lc   = lane & 15;
    const int vbase0 = blockIdx.x*256 + wid*64;   // wave's first voxel
    const int vown   = vbase0 + lane;             // this lane's own voxel

    // ---- wave-resident fragments ----
    half8_t w2a;   // A-frag of W2^T: A[m=lc][k=lq*8+j] = W2[k][m]
    #pragma unroll
    for (int j=0;j<8;++j) w2a[j] = (_Float16)W2[(lq*8+j)*16 + lc];
    half4_t w3a;   // A-frag of W3^T, rows 8..15 duplicate 0..7
    #pragma unroll
    for (int j=0;j<4;++j) w3a[j] = (_Float16)W3[(lq*4+j)*8 + (lc&7)];
    float4_t c1init, c2init;
    #pragma unroll
    for (int r=0;r<4;++r) {
        c1init[r] = b2[lq*4+r];
        c2init[r] = b3[(lq*4+r)&7];
    }
    half8_t b1h;   // bias for channel group lq
    #pragma unroll
    for (int j=0;j<8;++j) b1h[j] = (_Float16)b1[8*lq+j];

    // own-voxel coords
    {
    }
    int io  = vown % RR;
    int to  = vown / RR;
    int jo  = to % RR;
    int ko  = to / RR;
    const float step = 2.0f/(float)(RR-1);
    const float xo = fmaf((float)io, step, -1.0f);
    const float yo = fmaf((float)jo, step, -1.0f);
    const float zo = fmaf((float)ko, step, -1.0f);

    float accA[16], accB[16];
    #pragma unroll
    for (int q=0;q<16;++q) { accA[q]=0.f; accB[q]=0.f; }
    float accMown = 0.f;   // sum over views of own-voxel mask

    for (int v = 0; v < NVIEW; ++v) {
        const float* P = poses + v*16;               // uniform -> scalar
        // ---- own-voxel projection (once per view) ----
        float px = fmaf(P[0],xo, fmaf(P[1],yo, fmaf(P[2], zo, P[3])));
        float py = fmaf(P[4],xo, fmaf(P[5],yo, fmaf(P[6], zo, P[7])));
        float pz = fmaf(P[8],xo, fmaf(P[9],yo, fmaf(P[10],zo, P[11])));
        float r0 = __builtin_amdgcn_rcpf(pz);
        r0 = r0*(2.0f - pz*r0);                      // 1 Newton step
        float u  = px*r0;
        float w  = py*r0;
        bool mko = (pz > 0.f && u >= 0.f && u <= (float)(IW-1)
                              && w >= 0.f && w <= (float)(IH-1));
        accMown += mko ? 1.f : 0.f;

        float uc = fminf(fmaxf(u, 0.f), (float)(IW-1));
        float wc = fminf(fmaxf(w, 0.f), (float)(IH-1));
        float fx0 = floorf(uc), fy0 = floorf(wc);
        float tx = uc - fx0, ty = wc - fy0;
        int x0 = (int)fx0, y0 = (int)fy0;
        float wx0 = 1.f - tx, wy0 = 1.f - ty;

        half2_t wpA = { (_Float16)(wx0*wy0), (_Float16)(tx*wy0) };
        half2_t wpB = { (_Float16)(wx0*ty),  (_Float16)(tx*ty)  };
        int pk0 = __builtin_bit_cast(int, wpA);
        int pk1 = __builtin_bit_cast(int, wpB);
        int pk2 = ((y0*IW + x0)*8) | (mko ? (int)0x80000000 : 0);

        const _Float16* gp = G + (size_t)v*VIEW_H + (size_t)lq*PLANE_H;

        #pragma unroll
        for (int p=0;p<4;++p) {
            int addr = (16*p + lc) << 2;             // source lane * 4
            int s0 = __builtin_amdgcn_ds_bpermute(addr, pk0);
            int s1 = __builtin_amdgcn_ds_bpermute(addr, pk1);
            int s2 = __builtin_amdgcn_ds_bpermute(addr, pk2);
            half2_t wA = __builtin_bit_cast(half2_t, s0);
            half2_t wB = __builtin_bit_cast(half2_t, s1);
            int offp   = s2 & 0xFFFF;
            float mkf  = (float)((unsigned)s2 >> 31);

            const _Float16* base = gp + offp;
            half8_t a = *(const half8_t*)(base);
            half8_t b = *(const half8_t*)(base + 8);
            half8_t c = *(const half8_t*)(base + IW*8);
            half8_t d = *(const half8_t*)(base + IW*8 + 8);
            half8_t h1 = a*wA[0] + b*wA[1] + c*wB[0] + d*wB[1] + b1h;
            h1 = __builtin_elementwise_max(h1, (half8_t)(_Float16)0.f);

            // layer 2: D1[f2][vox]  (A = W2^T, B = H1^T in-register)
            float4_t d1 = __builtin_amdgcn_mfma_f32_16x16x32_f16(w2a, h1, c1init, 0,0,0);
            half4_t h2;
            #pragma unroll
            for (int r=0;r<4;++r) h2[r] = (_Float16)fmaxf(d1[r], 0.f);

            // layer 3: D2[fo'][vox]  (relu(D1) C-layout == B-frag for K=16)
            float4_t d2 = __builtin_amdgcn_mfma_f32_16x16x16f16(w3a, h2, c2init, 0,0,0);

            #pragma unroll
            for (int r=0;r<4;++r) {
                float h3 = d2[r];
                float tt = mkf*h3;
                accA[4*p+r] += tt;
                accB[4*p+r]  = fmaf(tt, h3, accB[4*p+r]);
            }
        }
    }

    // epilogue: accM for pass-p voxel lives in lane 16p+lc
    int accMi = __builtin_bit_cast(int, accMown);
    #pragma unroll
    for (int p=0;p<4;++p) {
        int addr = (16*p + lc) << 2;
        float accM = __builtin_bit_cast(float,
                        __builtin_amdgcn_ds_bpermute(addr, accMi));
        float S   = accM + 1e-8f;
        float inv = 1.f/S;
        float sw  = accM*inv;
        #pragma unroll
        for (int r=0;r<4;++r) {
            float mean = accA[4*p+r]*inv;
            float var  = fmaf(-mean*mean, (2.f - sw), accB[4*p+r]*inv);
            float val  = (lq < 2) ? mean : var;
            int   cch  = 4*lq + r;
            out[(size_t)cch*NVOX + vbase0 + 16*p + lc] = val;
        }
    }
}

extern "C" void kernel_launch(void* const* d_in, const int* in_sizes, int n_in,
                              void* d_out, int out_size, void* d_ws, size_t ws_size,
                              hipStream_t stream)
{
    const float* feats = (const float*)d_in[0];
    const float* poses = (const float*)d_in[1];
    const float* W1    = (const float*)d_in[2];
    const float* b1    = (const float*)d_in[3];
    const float* W2    = (const float*)d_in[4];
    const float* b2    = (const float*)d_in[5];
    const float* W3    = (const float*)d_in[6];
    const float* b3    = (const float*)d_in[7];
    float* out = (float*)d_out;

    _Float16* G = (_Float16*)d_ws;   // 1 MB
    g_precompute<<<256, 256, 0, stream>>>(feats, W1, G);
    dgfv_main<<<NVOX/256, 256, 0, stream>>>(G, poses, b1, W2, b2, W3, b3, out);
}

// Round 11
// 103.654 us; speedup vs baseline: 1.0254x; 1.0254x over previous
//
#include <hip/hip_runtime.h>
#include <cstddef>

#define RR 80
#define NVIEW 4
#define CH 32
#define IH 64
#define IW 64
#define NPIX (IH*IW)
#define NVOX (RR*RR*RR)   // 512000

// G (f16) layout: [v][grp(4 x 8ch)][y][x][8 f16 = 16B]
#define PLANE_H (NPIX*8)
#define VIEW_H  (4*PLANE_H)

typedef _Float16 half4_t  __attribute__((ext_vector_type(4)));
typedef _Float16 half8_t  __attribute__((ext_vector_type(8)));
typedef float    float4_t __attribute__((ext_vector_type(4)));

// ---------------------------------------------------------------------------
// G[v][g][y][x][e] = sum_ic feats[v][ic][y][x] * W1[ic][8*g+e]  (f16 output)
// ---------------------------------------------------------------------------
__global__ __launch_bounds__(256) void g_precompute(
    const float* __restrict__ feats, const float* __restrict__ W1,
    _Float16* __restrict__ G)
{
    int g = blockIdx.x >> 6;                        // 0..3 (8-ch group)
    int p = (blockIdx.x & 63)*256 + threadIdx.x;    // pixel 0..16383
    __shared__ float sW1[CH*8];
    if (threadIdx.x < CH*8) {
        int ic = threadIdx.x >> 3, e = threadIdx.x & 7;
        sW1[threadIdx.x] = W1[ic*CH + 8*g + e];
    }
    __syncthreads();
    int v  = p >> 12;
    int yx = p & 4095;
    const float* fb = feats + ((size_t)v*CH)*NPIX + yx;
    float acc[8];
    #pragma unroll
    for (int e=0;e<8;++e) acc[e] = 0.f;
    #pragma unroll
    for (int ic=0; ic<CH; ++ic) {
        float fv = fb[(size_t)ic*NPIX];
        #pragma unroll
        for (int e=0;e<8;++e) acc[e] = fmaf(fv, sW1[ic*8+e], acc[e]);
    }
    half8_t h;
    #pragma unroll
    for (int e=0;e<8;++e) h[e] = (_Float16)acc[e];
    *(half8_t*)(G + (size_t)v*VIEW_H + (size_t)g*PLANE_H + (size_t)yx*8) = h;
}

// ---------------------------------------------------------------------------
// Main: zero-LDS transposed MFMA MLP; pass-outer loop (small live set);
// clamp-based bounds (no per-corner tests — OOB contributions carry weight 0
// and x1/y1 overreads stay inside ws with zero weight / mk=0).
// NOTE (R10 post-mortem): do NOT dedup the per-quad projection via
// ds_bpermute — the lgkmcnt wait lands on the gather-address critical path
// and costs more than the redundant VALU (103.1 -> 106.3 µs regression).
// ---------------------------------------------------------------------------
__global__ __launch_bounds__(256) void dgfv_main(
    const _Float16* __restrict__ G,   // [NVIEW][4][IH][IW][8]
    const float* __restrict__ poses,
    const float* __restrict__ b1,
    const float* __restrict__ W2, const float* __restrict__ b2,
    const float* __restrict__ W3, const float* __restrict__ b3,
    float* __restrict__ out)
{
    const int wid  = threadIdx.x >> 6;
    const int lane = threadIdx.x & 63;
    const int lq   = lane >> 4;
    const int lc   = lane & 15;
    const int vbase = blockIdx.x*256 + wid*64 + lc;  // voxel of pass p: vbase+16p

    // ---- wave-resident fragments ----
    half8_t w2a;   // A-frag of W2^T: A[m=lc][k=lq*8+j] = W2[k][m]
    #pragma unroll
    for (int j=0;j<8;++j) w2a[j] = (_Float16)W2[(lq*8+j)*16 + lc];
    half4_t w3a;   // A-frag of W3^T, rows 8..15 duplicate 0..7
    #pragma unroll
    for (int j=0;j<4;++j) w3a[j] = (_Float16)W3[(lq*4+j)*8 + (lc&7)];
    float4_t c1init, c2init;
    #pragma unroll
    for (int r=0;r<4;++r) {
        c1init[r] = b2[lq*4+r];
        c2init[r] = b3[(lq*4+r)&7];
    }
    half8_t b1h;   // bias for channel group lq
    #pragma unroll
    for (int j=0;j<8;++j) b1h[j] = (_Float16)b1[8*lq+j];

    const float step = 2.0f/(float)(RR-1);

    #pragma unroll
    for (int p=0;p<4;++p) {
        int vx = vbase + 16*p;
        int i  = vx % RR;
        int t  = vx / RR;
        int j_ = t % RR;
        int k_ = t / RR;
        float x = fmaf((float)i,  step, -1.0f);
        float y = fmaf((float)j_, step, -1.0f);
        float z = fmaf((float)k_, step, -1.0f);

        float accA[4], accB[4], accM = 0.f;
        #pragma unroll
        for (int r=0;r<4;++r) { accA[r]=0.f; accB[r]=0.f; }

        #pragma unroll
        for (int v = 0; v < NVIEW; ++v) {
            const float* P = poses + v*16;           // uniform -> scalar
            float px = fmaf(P[0],x, fmaf(P[1],y, fmaf(P[2], z, P[3])));
            float py = fmaf(P[4],x, fmaf(P[5],y, fmaf(P[6], z, P[7])));
            float pz = fmaf(P[8],x, fmaf(P[9],y, fmaf(P[10],z, P[11])));
            float r0 = __builtin_amdgcn_rcpf(pz);
            r0 = r0*(2.0f - pz*r0);                  // 1 Newton step
            float u  = px*r0;
            float w  = py*r0;

            float mk = (pz > 0.f && u >= 0.f && u <= (float)(IW-1)
                                  && w >= 0.f && w <= (float)(IH-1)) ? 1.f : 0.f;

            // NaN-safe clamp; when mk==1 this is the identity
            float uc = fminf(fmaxf(u, 0.f), (float)(IW-1));
            float wc = fminf(fmaxf(w, 0.f), (float)(IH-1));
            float fx0 = floorf(uc), fy0 = floorf(wc);
            float tx = uc - fx0, ty = wc - fy0;
            int x0 = (int)fx0, y0 = (int)fy0;
            float wx0 = 1.f - tx, wy0 = 1.f - ty;

            _Float16 w00h = (_Float16)(wx0*wy0), w10h = (_Float16)(tx*wy0);
            _Float16 w01h = (_Float16)(wx0*ty),  w11h = (_Float16)(tx*ty);

            const _Float16* base = G + (size_t)v*VIEW_H + (size_t)lq*PLANE_H
                                     + (size_t)(y0*IW + x0)*8;
            half8_t a = *(const half8_t*)(base);
            half8_t b = *(const half8_t*)(base + 8);        // x1 (wt 0 if x0=63)
            half8_t c = *(const half8_t*)(base + IW*8);     // y1
            half8_t d = *(const half8_t*)(base + IW*8 + 8);
            half8_t h1 = a*w00h + b*w10h + c*w01h + d*w11h + b1h;
            h1 = __builtin_elementwise_max(h1, (half8_t)(_Float16)0.f);

            // layer 2: D1[f2][vox]  (A = W2^T, B = H1^T built in-register)
            float4_t d1 = __builtin_amdgcn_mfma_f32_16x16x32_f16(w2a, h1, c1init, 0,0,0);
            half4_t h2;
            #pragma unroll
            for (int r=0;r<4;++r) h2[r] = (_Float16)fmaxf(d1[r], 0.f);

            // layer 3: D2[fo'][vox]  (relu(D1) C-layout == B-frag for K=16)
            float4_t d2 = __builtin_amdgcn_mfma_f32_16x16x16f16(w3a, h2, c2init, 0,0,0);

            #pragma unroll
            for (int r=0;r<4;++r) {
                float h3 = d2[r];
                float tt = mk*h3;
                accA[r] += tt;
                accB[r]  = fmaf(tt, h3, accB[r]);
            }
            accM += mk;
        }

        // per-pass epilogue: quads 0,1 -> mean, quads 2,3 -> var
        float S   = accM + 1e-8f;
        float inv = 1.f/S;
        float sw  = accM*inv;
        #pragma unroll
        for (int r=0;r<4;++r) {
            float mean = accA[r]*inv;
            float var  = fmaf(-mean*mean, (2.f - sw), accB[r]*inv);
            float val  = (lq < 2) ? mean : var;
            int   cch  = 4*lq + r;
            out[(size_t)cch*NVOX + vx] = val;
        }
    }
}

extern "C" void kernel_launch(void* const* d_in, const int* in_sizes, int n_in,
                              void* d_out, int out_size, void* d_ws, size_t ws_size,
                              hipStream_t stream)
{
    const float* feats = (const float*)d_in[0];
    const float* poses = (const float*)d_in[1];
    const float* W1    = (const float*)d_in[2];
    const float* b1    = (const float*)d_in[3];
    const float* W2    = (const float*)d_in[4];
    const float* b2    = (const float*)d_in[5];
    const float* W3    = (const float*)d_in[6];
    const float* b3    = (const float*)d_in[7];
    float* out = (float*)d_out;

    _Float16* G = (_Float16*)d_ws;   // 1 MB
    g_precompute<<<256, 256, 0, stream>>>(feats, W1, G);
    dgfv_main<<<NVOX/256, 256, 0, stream>>>(G, poses, b1, W2, b2, W3, b3, out);
}